// Round 1
// baseline (101.321 us; speedup 1.0000x reference)
//
#include <hip/hip_runtime.h>
#include <math.h>

#define CANON_EPS 1e-4f

// ---------------------------------------------------------------------------
// Kernel 1: CSR boundaries from the sorted batch array.
// starts[g] = first atom index with batch >= g ; starts[G] = n.
// Every entry of starts[0..G] is written (no reliance on ws contents).
// ---------------------------------------------------------------------------
__global__ void build_starts_kernel(const int* __restrict__ batch,
                                    int* __restrict__ starts, int n, int G) {
  int i = blockIdx.x * blockDim.x + threadIdx.x;
  if (i >= n) return;
  int b = batch[i];
  int bp = (i == 0) ? -1 : batch[i - 1];
  for (int g = bp + 1; g <= b; ++g) starts[g] = i;
  if (i == n - 1) {
    for (int g = b + 1; g <= G; ++g) starts[g] = n;
  }
}

// ---------------------------------------------------------------------------
// 64-lane butterfly reductions (all lanes end with the total)
// ---------------------------------------------------------------------------
__device__ __forceinline__ float wave_sum(float v) {
  for (int off = 1; off < 64; off <<= 1) v += __shfl_xor(v, off);
  return v;
}
__device__ __forceinline__ double wave_sum_d(double v) {
  for (int off = 1; off < 64; off <<= 1) v += __shfl_xor(v, off);
  return v;
}

// ---------------------------------------------------------------------------
// 3x3 symmetric Jacobi eigensolver (double). Columns of Q = eigenvectors,
// eigenvalues sorted ascending (matches jnp.linalg.eigh ordering).
// ---------------------------------------------------------------------------
__device__ void jacobi3(double a00, double a11, double a22,
                        double a01, double a02, double a12,
                        double Q[3][3], double w[3]) {
  double A[3][3] = {{a00, a01, a02}, {a01, a11, a12}, {a02, a12, a22}};
  for (int i = 0; i < 3; ++i)
    for (int j = 0; j < 3; ++j) Q[i][j] = (i == j) ? 1.0 : 0.0;

  for (int sweep = 0; sweep < 30; ++sweep) {
    double off = A[0][1] * A[0][1] + A[0][2] * A[0][2] + A[1][2] * A[1][2];
    double diag = A[0][0] * A[0][0] + A[1][1] * A[1][1] + A[2][2] * A[2][2];
    if (off <= 1e-28 * (diag + 1e-300)) break;
    for (int p = 0; p < 2; ++p) {
      for (int q = p + 1; q < 3; ++q) {
        double apq = A[p][q];
        if (apq == 0.0) continue;
        double app = A[p][p], aqq = A[q][q];
        double tau = (aqq - app) / (2.0 * apq);
        double t = (tau >= 0.0 ? 1.0 : -1.0) / (fabs(tau) + sqrt(1.0 + tau * tau));
        double c = 1.0 / sqrt(1.0 + t * t);
        double s = t * c;
        A[p][p] = app - t * apq;
        A[q][q] = aqq + t * apq;
        A[p][q] = A[q][p] = 0.0;
        int k = 3 - p - q;  // the remaining index
        double akp = A[k][p], akq = A[k][q];
        A[k][p] = A[p][k] = c * akp - s * akq;
        A[k][q] = A[q][k] = s * akp + c * akq;
        for (int r = 0; r < 3; ++r) {
          double qrp = Q[r][p], qrq = Q[r][q];
          Q[r][p] = c * qrp - s * qrq;
          Q[r][q] = s * qrp + c * qrq;
        }
      }
    }
  }
  w[0] = A[0][0]; w[1] = A[1][1]; w[2] = A[2][2];
  // insertion sort ascending, swapping eigenvector columns along
  for (int i = 0; i < 2; ++i)
    for (int j = i + 1; j < 3; ++j)
      if (w[j] < w[i]) {
        double tw = w[i]; w[i] = w[j]; w[j] = tw;
        for (int r = 0; r < 3; ++r) {
          double tq = Q[r][i]; Q[r][i] = Q[r][j]; Q[r][j] = tq;
        }
      }
}

// ---------------------------------------------------------------------------
// Kernel 2: one 64-lane wave per graph.
// ---------------------------------------------------------------------------
__global__ __launch_bounds__(256) void canon_kernel(
    const float* __restrict__ pos, const int* __restrict__ starts,
    float* __restrict__ out, int G) {
  int gid = (int)((blockIdx.x * (unsigned)blockDim.x + threadIdx.x) >> 6);
  int lane = (int)(threadIdx.x & 63u);
  if (gid >= G) return;

  int s = starts[gid];
  int e = starts[gid + 1];
  int cnt = e - s;

  // ---- pass 1: centroid --------------------------------------------------
  float sx = 0.f, sy = 0.f, sz = 0.f;
  for (int i = s + lane; i < e; i += 64) {
    sx += pos[3 * i + 0];
    sy += pos[3 * i + 1];
    sz += pos[3 * i + 2];
  }
  sx = wave_sum(sx); sy = wave_sum(sy); sz = wave_sum(sz);
  float inv = 1.0f / fmaxf((float)cnt, 1.0f);
  float cx = sx * inv, cy = sy * inv, cz = sz * inv;

  // ---- pass 2: inertia tensor (6 unique components, f64 accumulation) ----
  double ixx = 0, iyy = 0, izz = 0, ixy = 0, ixz = 0, iyz = 0;
  for (int i = s + lane; i < e; i += 64) {
    float x = pos[3 * i + 0] - cx;
    float y = pos[3 * i + 1] - cy;
    float z = pos[3 * i + 2] - cz;
    ixx += (double)(y * y + z * z);
    iyy += (double)(x * x + z * z);
    izz += (double)(x * x + y * y);
    ixy -= (double)(x * y);
    ixz -= (double)(x * z);
    iyz -= (double)(y * z);
  }
  ixx = wave_sum_d(ixx); iyy = wave_sum_d(iyy); izz = wave_sum_d(izz);
  ixy = wave_sum_d(ixy); ixz = wave_sum_d(ixz); iyz = wave_sum_d(iyz);

  // ---- eigendecomposition: all lanes run it redundantly (identical data,
  //      lockstep, no broadcast needed afterwards) -------------------------
  double Q[3][3], w[3];
  jacobi3(ixx, iyy, izz, ixy, ixz, iyz, Q, w);

  float q00 = (float)Q[0][0], q10 = (float)Q[1][0], q20 = (float)Q[2][0];
  float q01 = (float)Q[0][1], q11 = (float)Q[1][1], q21 = (float)Q[2][1];

  // ---- pass 3: sign detection (first atom in original order with
  //      |proj| > EPS, per axis 0 and 1) -----------------------------------
  int found0 = 0, found1 = 0;
  float v0 = 0.f, v1 = 0.f;
  for (int base = s; base < e; base += 64) {
    int i = base + lane;
    bool valid = i < e;
    float p0 = 0.f, p1 = 0.f;
    if (valid) {
      float x = pos[3 * i + 0] - cx;
      float y = pos[3 * i + 1] - cy;
      float z = pos[3 * i + 2] - cz;
      p0 = x * q00 + y * q10 + z * q20;
      p1 = x * q01 + y * q11 + z * q21;
    }
    if (!found0) {
      unsigned long long m = __ballot(valid && (fabsf(p0) > CANON_EPS));
      if (m) {
        int l = __ffsll((unsigned long long)m) - 1;
        v0 = __shfl(p0, l);
        found0 = 1;
      }
    }
    if (!found1) {
      unsigned long long m = __ballot(valid && (fabsf(p1) > CANON_EPS));
      if (m) {
        int l = __ffsll((unsigned long long)m) - 1;
        v1 = __shfl(p1, l);
        found1 = 1;
      }
    }
    if (found0 && found1) break;
  }
  float s0 = (found0 && v0 < 0.f) ? -1.f : 1.f;
  float s1 = (found1 && v1 < 0.f) ? -1.f : 1.f;

  // ---- epilogue: q0, q1, q2 = cross(q0,q1); out[g,i,j] = q_j[i] ----------
  if (lane == 0) {
    float q0x = q00 * s0, q0y = q10 * s0, q0z = q20 * s0;
    float q1x = q01 * s1, q1y = q11 * s1, q1z = q21 * s1;
    float q2x = q0y * q1z - q0z * q1y;
    float q2y = q0z * q1x - q0x * q1z;
    float q2z = q0x * q1y - q0y * q1x;
    float* o = out + (size_t)gid * 9;
    o[0] = q0x; o[1] = q1x; o[2] = q2x;   // row 0
    o[3] = q0y; o[4] = q1y; o[5] = q2y;   // row 1
    o[6] = q0z; o[7] = q1z; o[8] = q2z;   // row 2
  }
}

extern "C" void kernel_launch(void* const* d_in, const int* in_sizes, int n_in,
                              void* d_out, int out_size, void* d_ws, size_t ws_size,
                              hipStream_t stream) {
  const float* pos = (const float*)d_in[0];
  const int* batch = (const int*)d_in[1];
  float* out = (float*)d_out;

  int n = in_sizes[0] / 3;      // N atoms
  int G = out_size / 9;         // graphs (output is [G,3,3])

  int* starts = (int*)d_ws;     // (G+1) ints

  build_starts_kernel<<<(n + 255) / 256, 256, 0, stream>>>(batch, starts, n, G);

  // one 64-lane wave per graph, 4 waves per 256-thread block
  int blocks = (G + 3) / 4;
  canon_kernel<<<blocks, 256, 0, stream>>>(pos, starts, out, G);
}

// Round 2
// 39.034 us; speedup vs baseline: 2.5957x; 2.5957x over previous
//
#include <hip/hip_runtime.h>
#include <math.h>

#define CANON_EPS 1e-4f

// ---------------------------------------------------------------------------
// Kernel 1: CSR boundaries from the sorted batch array.
// ---------------------------------------------------------------------------
__global__ void build_starts_kernel(const int* __restrict__ batch,
                                    int* __restrict__ starts, int n, int G) {
  int i = blockIdx.x * blockDim.x + threadIdx.x;
  if (i >= n) return;
  int b = batch[i];
  int bp = (i == 0) ? -1 : batch[i - 1];
  for (int g = bp + 1; g <= b; ++g) starts[g] = i;
  if (i == n - 1) {
    for (int g = b + 1; g <= G; ++g) starts[g] = n;
  }
}

// ---------------------------------------------------------------------------
// 16-lane butterfly reduction (xor masks 1,2,4,8 stay inside the subgroup).
// All 16 lanes of the subgroup end with the subgroup total.
// ---------------------------------------------------------------------------
__device__ __forceinline__ double red16_d(double v) {
  v += __shfl_xor(v, 1);
  v += __shfl_xor(v, 2);
  v += __shfl_xor(v, 4);
  v += __shfl_xor(v, 8);
  return v;
}

// ---------------------------------------------------------------------------
// Branch-free 3x3 symmetric Jacobi eigensolver in f32.
// Fixed 6 cyclic sweeps (quadratic convergence => ~f32 eps by sweep 4).
// Columns of Q = eigenvectors; eigenvalues sorted ascending (matches eigh).
// Fully unrolled, no data-dependent control flow: safe for per-subgroup data.
// ---------------------------------------------------------------------------
__device__ __forceinline__ void jacobi3_f32(float a00, float a11, float a22,
                                            float a01, float a02, float a12,
                                            float Q[3][3], float w[3]) {
  float A00 = a00, A11 = a11, A22 = a22;
  float A01 = a01, A02 = a02, A12 = a12;
  float Q00 = 1.f, Q01 = 0.f, Q02 = 0.f;
  float Q10 = 0.f, Q11 = 1.f, Q12 = 0.f;
  float Q20 = 0.f, Q21 = 0.f, Q22 = 1.f;

#define ROT(App, Aqq, Apq, Akp, Akq, Qrp0, Qrq0, Qrp1, Qrq1, Qrp2, Qrq2)     \
  {                                                                          \
    float apq = Apq;                                                         \
    float theta = (Aqq - App) / (2.0f * apq);                                \
    float t = copysignf(1.0f, theta) /                                       \
              (fabsf(theta) + sqrtf(1.0f + theta * theta));                  \
    t = (apq == 0.0f) ? 0.0f : t; /* kills 0/0 NaN path */                   \
    float c = 1.0f / sqrtf(1.0f + t * t);                                    \
    float s = t * c;                                                         \
    App = App - t * apq;                                                     \
    Aqq = Aqq + t * apq;                                                     \
    Apq = 0.0f;                                                              \
    float akp = Akp, akq = Akq;                                              \
    Akp = c * akp - s * akq;                                                 \
    Akq = s * akp + c * akq;                                                 \
    float r0p = Qrp0, r0q = Qrq0;                                            \
    Qrp0 = c * r0p - s * r0q;                                                \
    Qrq0 = s * r0p + c * r0q;                                                \
    float r1p = Qrp1, r1q = Qrq1;                                            \
    Qrp1 = c * r1p - s * r1q;                                                \
    Qrq1 = s * r1p + c * r1q;                                                \
    float r2p = Qrp2, r2q = Qrq2;                                            \
    Qrp2 = c * r2p - s * r2q;                                                \
    Qrq2 = s * r2p + c * r2q;                                                \
  }

#pragma unroll
  for (int sweep = 0; sweep < 6; ++sweep) {
    // (p,q)=(0,1), k=2 : off-pair elems A[k][p]=A02, A[k][q]=A12
    ROT(A00, A11, A01, A02, A12, Q00, Q01, Q10, Q11, Q20, Q21);
    // (p,q)=(0,2), k=1 : A[k][p]=A01, A[k][q]=A12
    ROT(A00, A22, A02, A01, A12, Q00, Q02, Q10, Q12, Q20, Q22);
    // (p,q)=(1,2), k=0 : A[k][p]=A01, A[k][q]=A02
    ROT(A11, A22, A12, A01, A02, Q01, Q02, Q11, Q12, Q21, Q22);
  }
#undef ROT

  float w0 = A00, w1 = A11, w2 = A22;
  // branchless 3-element sort network: (0,1), (1,2), (0,1); swap columns too
#define CSWAP(wa, wb, qa0, qb0, qa1, qb1, qa2, qb2)                          \
  {                                                                          \
    bool sw = (wb) < (wa);                                                   \
    float tw = wa; wa = sw ? wb : wa; wb = sw ? tw : wb;                     \
    float t0 = qa0; qa0 = sw ? qb0 : qa0; qb0 = sw ? t0 : qb0;               \
    float t1 = qa1; qa1 = sw ? qb1 : qa1; qb1 = sw ? t1 : qb1;               \
    float t2 = qa2; qa2 = sw ? qb2 : qa2; qb2 = sw ? t2 : qb2;               \
  }
  CSWAP(w0, w1, Q00, Q01, Q10, Q11, Q20, Q21);
  CSWAP(w1, w2, Q01, Q02, Q11, Q12, Q21, Q22);
  CSWAP(w0, w1, Q00, Q01, Q10, Q11, Q20, Q21);
#undef CSWAP

  Q[0][0] = Q00; Q[0][1] = Q01; Q[0][2] = Q02;
  Q[1][0] = Q10; Q[1][1] = Q11; Q[1][2] = Q12;
  Q[2][0] = Q20; Q[2][1] = Q21; Q[2][2] = Q22;
  w[0] = w0; w[1] = w1; w[2] = w2;
}

// ---------------------------------------------------------------------------
// Kernel 2: 16 lanes per graph, 4 graphs per wave, 16 graphs per 256-block.
// ---------------------------------------------------------------------------
__global__ __launch_bounds__(256) void canon_kernel(
    const float* __restrict__ pos, const int* __restrict__ starts,
    float* __restrict__ out, int G) {
  int tid = (int)(blockIdx.x * (unsigned)blockDim.x + threadIdx.x);
  int gid = tid >> 4;                  // one graph per 16 lanes
  int lane = (int)(threadIdx.x & 63u); // lane within wave
  int subw = lane >> 4;                // subgroup index within wave (0..3)
  int sublane = lane & 15;             // lane within subgroup
  if (gid >= G) return;

  int s = starts[gid];
  int e = starts[gid + 1];
  int cnt = e - s;

  // ---- single pass: raw moments in f64 -----------------------------------
  double sx = 0, sy = 0, sz = 0;
  double sxx = 0, syy = 0, szz = 0, sxy = 0, sxz = 0, syz = 0;
  for (int i = s + sublane; i < e; i += 16) {
    float x = pos[3 * i + 0];
    float y = pos[3 * i + 1];
    float z = pos[3 * i + 2];
    sx += (double)x; sy += (double)y; sz += (double)z;
    sxx += (double)(x * x); syy += (double)(y * y); szz += (double)(z * z);
    sxy += (double)(x * y); sxz += (double)(x * z); syz += (double)(y * z);
  }
  sx = red16_d(sx); sy = red16_d(sy); sz = red16_d(sz);
  sxx = red16_d(sxx); syy = red16_d(syy); szz = red16_d(szz);
  sxy = red16_d(sxy); sxz = red16_d(sxz); syz = red16_d(syz);

  double dn = (double)(cnt > 0 ? cnt : 1);
  double mx = sx / dn, my = sy / dn, mz = sz / dn;
  // central second moments: Sab = sum(ab) - n*ma*mb  (exact in f64)
  double Sxx = sxx - dn * mx * mx;
  double Syy = syy - dn * my * my;
  double Szz = szz - dn * mz * mz;
  double Sxy = sxy - dn * mx * my;
  double Sxz = sxz - dn * mx * mz;
  double Syz = syz - dn * my * mz;

  // inertia tensor: I = tr(S)*Id - S  (diag: sum of other two; offdiag: -S)
  float ixx = (float)(Syy + Szz);
  float iyy = (float)(Sxx + Szz);
  float izz = (float)(Sxx + Syy);
  float ixy = (float)(-Sxy);
  float ixz = (float)(-Sxz);
  float iyz = (float)(-Syz);

  float cx = (float)mx, cy = (float)my, cz = (float)mz;

  // ---- eigendecomposition (per-subgroup data, branch-free) ---------------
  float Q[3][3], w[3];
  jacobi3_f32(ixx, iyy, izz, ixy, ixz, iyz, Q, w);

  float q00 = Q[0][0], q10 = Q[1][0], q20 = Q[2][0];
  float q01 = Q[0][1], q11 = Q[1][1], q21 = Q[2][1];

  // ---- sign detection: first atom (original order) with |proj| > EPS -----
  bool found0 = false, found1 = false;
  float v0 = 0.f, v1 = 0.f;
  int it = 0;
  while (true) {
    int i = s + it * 16 + sublane;
    bool in = i < e;
    float p0 = 0.f, p1 = 0.f;
    if (in) {
      float x = pos[3 * i + 0] - cx;
      float y = pos[3 * i + 1] - cy;
      float z = pos[3 * i + 2] - cz;
      p0 = x * q00 + y * q10 + z * q20;
      p1 = x * q01 + y * q11 + z * q21;
    }
    unsigned long long b0 = __ballot(in && (fabsf(p0) > CANON_EPS));
    unsigned long long b1 = __ballot(in && (fabsf(p1) > CANON_EPS));
    unsigned m0 = (unsigned)((b0 >> (subw * 16)) & 0xFFFFull);
    unsigned m1 = (unsigned)((b1 >> (subw * 16)) & 0xFFFFull);
    if (!found0 && m0) {
      int l = __ffs(m0) - 1;
      v0 = __shfl(p0, subw * 16 + l);
      found0 = true;
    }
    if (!found1 && m1) {
      int l = __ffs(m1) - 1;
      v1 = __shfl(p1, subw * 16 + l);
      found1 = true;
    }
    bool exhausted = (s + it * 16) >= e;
    bool mydone = (found0 && found1) || exhausted;
    if (__all(mydone)) break;
    ++it;
  }
  float s0 = (found0 && v0 < 0.f) ? -1.f : 1.f;
  float s1 = (found1 && v1 < 0.f) ? -1.f : 1.f;

  // ---- epilogue ----------------------------------------------------------
  if (sublane == 0) {
    float q0x = q00 * s0, q0y = q10 * s0, q0z = q20 * s0;
    float q1x = q01 * s1, q1y = q11 * s1, q1z = q21 * s1;
    float q2x = q0y * q1z - q0z * q1y;
    float q2y = q0z * q1x - q0x * q1z;
    float q2z = q0x * q1y - q0y * q1x;
    float* o = out + (size_t)gid * 9;
    o[0] = q0x; o[1] = q1x; o[2] = q2x;
    o[3] = q0y; o[4] = q1y; o[5] = q2y;
    o[6] = q0z; o[7] = q1z; o[8] = q2z;
  }
}

extern "C" void kernel_launch(void* const* d_in, const int* in_sizes, int n_in,
                              void* d_out, int out_size, void* d_ws, size_t ws_size,
                              hipStream_t stream) {
  const float* pos = (const float*)d_in[0];
  const int* batch = (const int*)d_in[1];
  float* out = (float*)d_out;

  int n = in_sizes[0] / 3;  // N atoms
  int G = out_size / 9;     // graphs

  int* starts = (int*)d_ws;  // (G+1) ints

  build_starts_kernel<<<(n + 255) / 256, 256, 0, stream>>>(batch, starts, n, G);

  // 16 lanes per graph -> 16 graphs per 256-thread block
  int blocks = (G + 15) / 16;
  canon_kernel<<<blocks, 256, 0, stream>>>(pos, starts, out, G);
}

// Round 3
// 26.116 us; speedup vs baseline: 3.8797x; 1.4946x over previous
//
#include <hip/hip_runtime.h>
#include <math.h>

#define CANON_EPS 1e-4f
#define SUB 8          // lanes per graph
#define SUBMASK 0xFFu  // SUB-wide ballot mask

// ---------------------------------------------------------------------------
// Kernel 1: CSR boundaries from the sorted batch array.
// ---------------------------------------------------------------------------
__global__ void build_starts_kernel(const int* __restrict__ batch,
                                    int* __restrict__ starts, int n, int G) {
  int i = blockIdx.x * blockDim.x + threadIdx.x;
  if (i >= n) return;
  int b = batch[i];
  int bp = (i == 0) ? -1 : batch[i - 1];
  for (int g = bp + 1; g <= b; ++g) starts[g] = i;
  if (i == n - 1) {
    for (int g = b + 1; g <= G; ++g) starts[g] = n;
  }
}

// ---------------------------------------------------------------------------
// 8-lane butterfly reduction (xor masks 1,2,4 stay inside the subgroup).
// ---------------------------------------------------------------------------
__device__ __forceinline__ float red8(float v) {
  v += __shfl_xor(v, 1);
  v += __shfl_xor(v, 2);
  v += __shfl_xor(v, 4);
  return v;
}

// ---------------------------------------------------------------------------
// Branch-free 3x3 symmetric Jacobi eigensolver in f32, 5 cyclic sweeps.
// Columns of Q = eigenvectors; eigenvalues sorted ascending (matches eigh).
// ---------------------------------------------------------------------------
__device__ __forceinline__ void jacobi3_f32(float a00, float a11, float a22,
                                            float a01, float a02, float a12,
                                            float Q[3][3]) {
  float A00 = a00, A11 = a11, A22 = a22;
  float A01 = a01, A02 = a02, A12 = a12;
  float Q00 = 1.f, Q01 = 0.f, Q02 = 0.f;
  float Q10 = 0.f, Q11 = 1.f, Q12 = 0.f;
  float Q20 = 0.f, Q21 = 0.f, Q22 = 1.f;

#define ROT(App, Aqq, Apq, Akp, Akq, Qrp0, Qrq0, Qrp1, Qrq1, Qrp2, Qrq2)     \
  {                                                                          \
    float apq = Apq;                                                         \
    float theta = (Aqq - App) / (2.0f * apq);                                \
    float t = copysignf(1.0f, theta) /                                       \
              (fabsf(theta) + sqrtf(1.0f + theta * theta));                  \
    t = (apq == 0.0f) ? 0.0f : t; /* kills 0/0 NaN path */                   \
    float c = 1.0f / sqrtf(1.0f + t * t);                                    \
    float s = t * c;                                                         \
    App = App - t * apq;                                                     \
    Aqq = Aqq + t * apq;                                                     \
    Apq = 0.0f;                                                              \
    float akp = Akp, akq = Akq;                                              \
    Akp = c * akp - s * akq;                                                 \
    Akq = s * akp + c * akq;                                                 \
    float r0p = Qrp0, r0q = Qrq0;                                            \
    Qrp0 = c * r0p - s * r0q;                                                \
    Qrq0 = s * r0p + c * r0q;                                                \
    float r1p = Qrp1, r1q = Qrq1;                                            \
    Qrp1 = c * r1p - s * r1q;                                                \
    Qrq1 = s * r1p + c * r1q;                                                \
    float r2p = Qrp2, r2q = Qrq2;                                            \
    Qrp2 = c * r2p - s * r2q;                                                \
    Qrq2 = s * r2p + c * r2q;                                                \
  }

#pragma unroll
  for (int sweep = 0; sweep < 5; ++sweep) {
    ROT(A00, A11, A01, A02, A12, Q00, Q01, Q10, Q11, Q20, Q21);
    ROT(A00, A22, A02, A01, A12, Q00, Q02, Q10, Q12, Q20, Q22);
    ROT(A11, A22, A12, A01, A02, Q01, Q02, Q11, Q12, Q21, Q22);
  }
#undef ROT

  float w0 = A00, w1 = A11, w2 = A22;
#define CSWAP(wa, wb, qa0, qb0, qa1, qb1, qa2, qb2)                          \
  {                                                                          \
    bool sw = (wb) < (wa);                                                   \
    float tw = wa; wa = sw ? wb : wa; wb = sw ? tw : wb;                     \
    float t0 = qa0; qa0 = sw ? qb0 : qa0; qb0 = sw ? t0 : qb0;               \
    float t1 = qa1; qa1 = sw ? qb1 : qa1; qb1 = sw ? t1 : qb1;               \
    float t2 = qa2; qa2 = sw ? qb2 : qa2; qb2 = sw ? t2 : qb2;               \
  }
  CSWAP(w0, w1, Q00, Q01, Q10, Q11, Q20, Q21);
  CSWAP(w1, w2, Q01, Q02, Q11, Q12, Q21, Q22);
  CSWAP(w0, w1, Q00, Q01, Q10, Q11, Q20, Q21);
#undef CSWAP

  Q[0][0] = Q00; Q[0][1] = Q01; Q[0][2] = Q02;
  Q[1][0] = Q10; Q[1][1] = Q11; Q[1][2] = Q12;
  Q[2][0] = Q20; Q[2][1] = Q21; Q[2][2] = Q22;
}

// ---------------------------------------------------------------------------
// Kernel 2: 8 lanes per graph, 8 graphs per wave, 32 graphs per 256-block.
// ---------------------------------------------------------------------------
__global__ __launch_bounds__(256) void canon_kernel(
    const float* __restrict__ pos, const int* __restrict__ starts,
    float* __restrict__ out, int G) {
  int tid = (int)(blockIdx.x * (unsigned)blockDim.x + threadIdx.x);
  int gid = tid / SUB;
  int lane = (int)(threadIdx.x & 63u);
  int subw = lane / SUB;      // subgroup index within wave
  int sublane = lane & (SUB - 1);
  if (gid >= G) return;

  int s = starts[gid];
  int e = starts[gid + 1];
  int cnt = e - s;

  // ---- single pass: raw moments, all f32 (FMA-friendly) ------------------
  float sx = 0.f, sy = 0.f, sz = 0.f;
  float sxx = 0.f, syy = 0.f, szz = 0.f, sxy = 0.f, sxz = 0.f, syz = 0.f;
  for (int i = s + sublane; i < e; i += SUB) {
    float x = pos[3 * i + 0];
    float y = pos[3 * i + 1];
    float z = pos[3 * i + 2];
    sx += x; sy += y; sz += z;
    sxx = fmaf(x, x, sxx); syy = fmaf(y, y, syy); szz = fmaf(z, z, szz);
    sxy = fmaf(x, y, sxy); sxz = fmaf(x, z, sxz); syz = fmaf(y, z, syz);
  }
  sx = red8(sx); sy = red8(sy); sz = red8(sz);
  sxx = red8(sxx); syy = red8(syy); szz = red8(szz);
  sxy = red8(sxy); sxz = red8(sxz); syz = red8(syz);

  float fn = (float)(cnt > 0 ? cnt : 1);
  float inv = 1.0f / fn;
  float mx = sx * inv, my = sy * inv, mz = sz * inv;
  // central second moments: Sab = sum(ab) - n*ma*mb
  float Sxx = fmaf(-fn * mx, mx, sxx);
  float Syy = fmaf(-fn * my, my, syy);
  float Szz = fmaf(-fn * mz, mz, szz);
  float Sxy = fmaf(-fn * mx, my, sxy);
  float Sxz = fmaf(-fn * mx, mz, sxz);
  float Syz = fmaf(-fn * my, mz, syz);

  // inertia tensor: I = tr(S)*Id - S
  float ixx = Syy + Szz;
  float iyy = Sxx + Szz;
  float izz = Sxx + Syy;
  float ixy = -Sxy;
  float ixz = -Sxz;
  float iyz = -Syz;

  // ---- eigendecomposition (branch-free, replicated per subgroup) ---------
  float Q[3][3];
  jacobi3_f32(ixx, iyy, izz, ixy, ixz, iyz, Q);

  float q00 = Q[0][0], q10 = Q[1][0], q20 = Q[2][0];
  float q01 = Q[0][1], q11 = Q[1][1], q21 = Q[2][1];

  // ---- sign detection: first atom (original order) with |proj| > EPS -----
  bool found0 = false, found1 = false;
  float v0 = 0.f, v1 = 0.f;
  int it = 0;
  while (true) {
    int i = s + it * SUB + sublane;
    bool in = i < e;
    float p0 = 0.f, p1 = 0.f;
    if (in) {
      float x = pos[3 * i + 0] - mx;
      float y = pos[3 * i + 1] - my;
      float z = pos[3 * i + 2] - mz;
      p0 = x * q00 + y * q10 + z * q20;
      p1 = x * q01 + y * q11 + z * q21;
    }
    unsigned long long b0 = __ballot(in && (fabsf(p0) > CANON_EPS));
    unsigned long long b1 = __ballot(in && (fabsf(p1) > CANON_EPS));
    unsigned m0 = (unsigned)((b0 >> (subw * SUB)) & SUBMASK);
    unsigned m1 = (unsigned)((b1 >> (subw * SUB)) & SUBMASK);
    if (!found0 && m0) {
      int l = __ffs(m0) - 1;
      v0 = __shfl(p0, subw * SUB + l);
      found0 = true;
    }
    if (!found1 && m1) {
      int l = __ffs(m1) - 1;
      v1 = __shfl(p1, subw * SUB + l);
      found1 = true;
    }
    bool exhausted = (s + it * SUB) >= e;
    bool mydone = (found0 && found1) || exhausted;
    if (__all(mydone)) break;
    ++it;
  }
  float s0 = (found0 && v0 < 0.f) ? -1.f : 1.f;
  float s1 = (found1 && v1 < 0.f) ? -1.f : 1.f;

  // ---- epilogue ----------------------------------------------------------
  if (sublane == 0) {
    float q0x = q00 * s0, q0y = q10 * s0, q0z = q20 * s0;
    float q1x = q01 * s1, q1y = q11 * s1, q1z = q21 * s1;
    float q2x = q0y * q1z - q0z * q1y;
    float q2y = q0z * q1x - q0x * q1z;
    float q2z = q0x * q1y - q0y * q1x;
    float* o = out + (size_t)gid * 9;
    o[0] = q0x; o[1] = q1x; o[2] = q2x;
    o[3] = q0y; o[4] = q1y; o[5] = q2y;
    o[6] = q0z; o[7] = q1z; o[8] = q2z;
  }
}

extern "C" void kernel_launch(void* const* d_in, const int* in_sizes, int n_in,
                              void* d_out, int out_size, void* d_ws, size_t ws_size,
                              hipStream_t stream) {
  const float* pos = (const float*)d_in[0];
  const int* batch = (const int*)d_in[1];
  float* out = (float*)d_out;

  int n = in_sizes[0] / 3;  // N atoms
  int G = out_size / 9;     // graphs

  int* starts = (int*)d_ws;  // (G+1) ints

  build_starts_kernel<<<(n + 255) / 256, 256, 0, stream>>>(batch, starts, n, G);

  // SUB lanes per graph -> 256/SUB graphs per block
  int gper = 256 / SUB;
  int blocks = (G + gper - 1) / gper;
  canon_kernel<<<blocks, 256, 0, stream>>>(pos, starts, out, G);
}

// Round 4
// 23.684 us; speedup vs baseline: 4.2781x; 1.1027x over previous
//
#include <hip/hip_runtime.h>
#include <math.h>

#define CANON_EPS 1e-4f
#define SUBA 16  // lanes per graph in the moments pass

// ---------------------------------------------------------------------------
// Kernel 1: CSR boundaries from the sorted batch array.
// ---------------------------------------------------------------------------
__global__ void build_starts_kernel(const int* __restrict__ batch,
                                    int* __restrict__ starts, int n, int G) {
  int i = blockIdx.x * blockDim.x + threadIdx.x;
  if (i >= n) return;
  int b = batch[i];
  int bp = (i == 0) ? -1 : batch[i - 1];
  for (int g = bp + 1; g <= b; ++g) starts[g] = i;
  if (i == n - 1) {
    for (int g = b + 1; g <= G; ++g) starts[g] = n;
  }
}

// ---------------------------------------------------------------------------
// 16-lane butterfly reduction (xor masks 1,2,4,8 stay inside the subgroup).
// ---------------------------------------------------------------------------
__device__ __forceinline__ float red16(float v) {
  v += __shfl_xor(v, 1);
  v += __shfl_xor(v, 2);
  v += __shfl_xor(v, 4);
  v += __shfl_xor(v, 8);
  return v;
}

// ---------------------------------------------------------------------------
// Kernel 2: moments per graph. 16 lanes/graph, 16 graphs per 256-block.
// Writes 9 floats per graph to ws in SoA layout: comp[c*G + g],
// c = 0..8 : cx, cy, cz, ixx, iyy, izz, ixy, ixz, iyz.
// ---------------------------------------------------------------------------
__global__ __launch_bounds__(256) void moments_kernel(
    const float* __restrict__ pos, const int* __restrict__ starts,
    float* __restrict__ wsf, int G) {
  int tid = (int)(blockIdx.x * (unsigned)blockDim.x + threadIdx.x);
  int gid = tid / SUBA;
  int sublane = tid & (SUBA - 1);
  if (gid >= G) return;

  int s = starts[gid];
  int e = starts[gid + 1];
  int cnt = e - s;

  float sx = 0.f, sy = 0.f, sz = 0.f;
  float sxx = 0.f, syy = 0.f, szz = 0.f, sxy = 0.f, sxz = 0.f, syz = 0.f;
  for (int i = s + sublane; i < e; i += SUBA) {
    float x = pos[3 * i + 0];
    float y = pos[3 * i + 1];
    float z = pos[3 * i + 2];
    sx += x; sy += y; sz += z;
    sxx = fmaf(x, x, sxx); syy = fmaf(y, y, syy); szz = fmaf(z, z, szz);
    sxy = fmaf(x, y, sxy); sxz = fmaf(x, z, sxz); syz = fmaf(y, z, syz);
  }
  sx = red16(sx); sy = red16(sy); sz = red16(sz);
  sxx = red16(sxx); syy = red16(syy); szz = red16(szz);
  sxy = red16(sxy); sxz = red16(sxz); syz = red16(syz);

  float fn = (float)(cnt > 0 ? cnt : 1);
  float inv = 1.0f / fn;
  float mx = sx * inv, my = sy * inv, mz = sz * inv;
  // central second moments: Sab = sum(ab) - n*ma*mb
  float Sxx = fmaf(-fn * mx, mx, sxx);
  float Syy = fmaf(-fn * my, my, syy);
  float Szz = fmaf(-fn * mz, mz, szz);
  float Sxy = fmaf(-fn * mx, my, sxy);
  float Sxz = fmaf(-fn * mx, mz, sxz);
  float Syz = fmaf(-fn * my, mz, syz);

  // inertia tensor: I = tr(S)*Id - S ; component select (no runtime array idx)
  float v = mx;                       // c=0
  v = (sublane == 1) ? my : v;
  v = (sublane == 2) ? mz : v;
  v = (sublane == 3) ? (Syy + Szz) : v;   // ixx
  v = (sublane == 4) ? (Sxx + Szz) : v;   // iyy
  v = (sublane == 5) ? (Sxx + Syy) : v;   // izz
  v = (sublane == 6) ? (-Sxy) : v;        // ixy
  v = (sublane == 7) ? (-Sxz) : v;        // ixz
  v = (sublane == 8) ? (-Syz) : v;        // iyz
  if (sublane < 9) wsf[sublane * G + gid] = v;
}

// ---------------------------------------------------------------------------
// Branch-free 3x3 symmetric Jacobi eigensolver in f32, 5 cyclic sweeps.
// Columns of Q = eigenvectors; eigenvalues sorted ascending (matches eigh).
// ---------------------------------------------------------------------------
__device__ __forceinline__ void jacobi3_f32(float a00, float a11, float a22,
                                            float a01, float a02, float a12,
                                            float Q[3][3]) {
  float A00 = a00, A11 = a11, A22 = a22;
  float A01 = a01, A02 = a02, A12 = a12;
  float Q00 = 1.f, Q01 = 0.f, Q02 = 0.f;
  float Q10 = 0.f, Q11 = 1.f, Q12 = 0.f;
  float Q20 = 0.f, Q21 = 0.f, Q22 = 1.f;

#define ROT(App, Aqq, Apq, Akp, Akq, Qrp0, Qrq0, Qrp1, Qrq1, Qrp2, Qrq2)     \
  {                                                                          \
    float apq = Apq;                                                         \
    float theta = (Aqq - App) / (2.0f * apq);                                \
    float t = copysignf(1.0f, theta) /                                       \
              (fabsf(theta) + sqrtf(1.0f + theta * theta));                  \
    t = (apq == 0.0f) ? 0.0f : t; /* kills 0/0 NaN path */                   \
    float c = 1.0f / sqrtf(1.0f + t * t);                                    \
    float s = t * c;                                                         \
    App = App - t * apq;                                                     \
    Aqq = Aqq + t * apq;                                                     \
    Apq = 0.0f;                                                              \
    float akp = Akp, akq = Akq;                                              \
    Akp = c * akp - s * akq;                                                 \
    Akq = s * akp + c * akq;                                                 \
    float r0p = Qrp0, r0q = Qrq0;                                            \
    Qrp0 = c * r0p - s * r0q;                                                \
    Qrq0 = s * r0p + c * r0q;                                                \
    float r1p = Qrp1, r1q = Qrq1;                                            \
    Qrp1 = c * r1p - s * r1q;                                                \
    Qrq1 = s * r1p + c * r1q;                                                \
    float r2p = Qrp2, r2q = Qrq2;                                            \
    Qrp2 = c * r2p - s * r2q;                                                \
    Qrq2 = s * r2p + c * r2q;                                                \
  }

#pragma unroll
  for (int sweep = 0; sweep < 5; ++sweep) {
    ROT(A00, A11, A01, A02, A12, Q00, Q01, Q10, Q11, Q20, Q21);
    ROT(A00, A22, A02, A01, A12, Q00, Q02, Q10, Q12, Q20, Q22);
    ROT(A11, A22, A12, A01, A02, Q01, Q02, Q11, Q12, Q21, Q22);
  }
#undef ROT

  float w0 = A00, w1 = A11, w2 = A22;
#define CSWAP(wa, wb, qa0, qb0, qa1, qb1, qa2, qb2)                          \
  {                                                                          \
    bool sw = (wb) < (wa);                                                   \
    float tw = wa; wa = sw ? wb : wa; wb = sw ? tw : wb;                     \
    float t0 = qa0; qa0 = sw ? qb0 : qa0; qb0 = sw ? t0 : qb0;               \
    float t1 = qa1; qa1 = sw ? qb1 : qa1; qb1 = sw ? t1 : qb1;               \
    float t2 = qa2; qa2 = sw ? qb2 : qa2; qb2 = sw ? t2 : qb2;               \
  }
  CSWAP(w0, w1, Q00, Q01, Q10, Q11, Q20, Q21);
  CSWAP(w1, w2, Q01, Q02, Q11, Q12, Q21, Q22);
  CSWAP(w0, w1, Q00, Q01, Q10, Q11, Q20, Q21);
#undef CSWAP

  Q[0][0] = Q00; Q[0][1] = Q01; Q[0][2] = Q02;
  Q[1][0] = Q10; Q[1][1] = Q11; Q[1][2] = Q12;
  Q[2][0] = Q20; Q[2][1] = Q21; Q[2][2] = Q22;
}

// ---------------------------------------------------------------------------
// Kernel 3: one lane per graph. Per-lane Jacobi (no replication), per-lane
// serial sign scan (expected ~1 atom for random data), epilogue + write.
// ---------------------------------------------------------------------------
__global__ __launch_bounds__(64) void eigen_kernel(
    const float* __restrict__ pos, const int* __restrict__ starts,
    const float* __restrict__ wsf, float* __restrict__ out, int G) {
  int g = (int)(blockIdx.x * (unsigned)blockDim.x + threadIdx.x);
  if (g >= G) return;

  float cx  = wsf[0 * G + g];
  float cy  = wsf[1 * G + g];
  float cz  = wsf[2 * G + g];
  float ixx = wsf[3 * G + g];
  float iyy = wsf[4 * G + g];
  float izz = wsf[5 * G + g];
  float ixy = wsf[6 * G + g];
  float ixz = wsf[7 * G + g];
  float iyz = wsf[8 * G + g];

  float Q[3][3];
  jacobi3_f32(ixx, iyy, izz, ixy, ixz, iyz, Q);

  float q00 = Q[0][0], q10 = Q[1][0], q20 = Q[2][0];
  float q01 = Q[0][1], q11 = Q[1][1], q21 = Q[2][1];

  int s = starts[g];
  int e = starts[g + 1];

  // first atom (original order) with |proj| > EPS, axes 0 and 1 independent
  bool found0 = false, found1 = false;
  float v0 = 0.f, v1 = 0.f;
  for (int i = s; i < e; ++i) {
    float x = pos[3 * i + 0] - cx;
    float y = pos[3 * i + 1] - cy;
    float z = pos[3 * i + 2] - cz;
    float p0 = x * q00 + y * q10 + z * q20;
    float p1 = x * q01 + y * q11 + z * q21;
    if (!found0 && fabsf(p0) > CANON_EPS) { v0 = p0; found0 = true; }
    if (!found1 && fabsf(p1) > CANON_EPS) { v1 = p1; found1 = true; }
    if (found0 && found1) break;
  }
  float s0 = (found0 && v0 < 0.f) ? -1.f : 1.f;
  float s1 = (found1 && v1 < 0.f) ? -1.f : 1.f;

  float q0x = q00 * s0, q0y = q10 * s0, q0z = q20 * s0;
  float q1x = q01 * s1, q1y = q11 * s1, q1z = q21 * s1;
  float q2x = q0y * q1z - q0z * q1y;
  float q2y = q0z * q1x - q0x * q1z;
  float q2z = q0x * q1y - q0y * q1x;
  float* o = out + (size_t)g * 9;
  o[0] = q0x; o[1] = q1x; o[2] = q2x;
  o[3] = q0y; o[4] = q1y; o[5] = q2y;
  o[6] = q0z; o[7] = q1z; o[8] = q2z;
}

extern "C" void kernel_launch(void* const* d_in, const int* in_sizes, int n_in,
                              void* d_out, int out_size, void* d_ws, size_t ws_size,
                              hipStream_t stream) {
  const float* pos = (const float*)d_in[0];
  const int* batch = (const int*)d_in[1];
  float* out = (float*)d_out;

  int n = in_sizes[0] / 3;  // N atoms
  int G = out_size / 9;     // graphs

  int* starts = (int*)d_ws;                  // (G+1) ints
  float* wsf = (float*)((char*)d_ws + ((size_t)(G + 1) * 4 + 255 & ~255ull));
  // wsf: 9 * G floats, SoA

  build_starts_kernel<<<(n + 255) / 256, 256, 0, stream>>>(batch, starts, n, G);

  int gperA = 256 / SUBA;  // graphs per block in moments pass
  moments_kernel<<<(G + gperA - 1) / gperA, 256, 0, stream>>>(pos, starts, wsf, G);

  eigen_kernel<<<(G + 63) / 64, 64, 0, stream>>>(pos, starts, wsf, out, G);
}

// Round 5
// 23.461 us; speedup vs baseline: 4.3188x; 1.0095x over previous
//
#include <hip/hip_runtime.h>
#include <math.h>

#define CANON_EPS 1e-4f

// ---------------------------------------------------------------------------
// Kernel A: fused bounds (binary search) + moments. 8 lanes per graph,
// 32 graphs per 256-thread block.
// Writes: wsi[g] = start of graph g (and wsi[G] = n), plus 9 floats/graph in
// SoA layout wsf[c*G + g], c = 0..8 : cx, cy, cz, ixx, iyy, izz, ixy, ixz, iyz.
// ---------------------------------------------------------------------------
__global__ __launch_bounds__(256) void moments_kernel(
    const float* __restrict__ pos, const int* __restrict__ batch,
    int* __restrict__ wsi, float* __restrict__ wsf, int n, int G) {
  int tid = (int)(blockIdx.x * (unsigned)blockDim.x + threadIdx.x);
  int gid = tid >> 3;            // 8 lanes per graph
  int sub = tid & 7;             // lane within subgroup
  int lane = (int)(threadIdx.x & 63u);
  if (gid >= G) return;

  // ---- bounds via binary search: lanes sub=0 -> lb(g), sub=1 -> lb(g+1) ---
  // (other lanes run a redundant search; loads broadcast from cache)
  int target = gid + (sub & 1);
  int lo = 0, hi = n;
  while (lo < hi) {
    int mid = (lo + hi) >> 1;
    bool less = batch[mid] < target;
    lo = less ? mid + 1 : lo;
    hi = less ? hi : mid;
  }
  int base = lane & ~7;
  int s = __shfl(lo, base);
  int e = __shfl(lo, base + 1);
  if (sub == 0) wsi[gid] = s;
  if (sub == 1 && gid == G - 1) wsi[G] = lo;  // lb(G) == n

  int cnt = e - s;

  // ---- raw moments, all f32 ----------------------------------------------
  float sx = 0.f, sy = 0.f, sz = 0.f;
  float sxx = 0.f, syy = 0.f, szz = 0.f, sxy = 0.f, sxz = 0.f, syz = 0.f;
  for (int i = s + sub; i < e; i += 8) {
    float x = pos[3 * i + 0];
    float y = pos[3 * i + 1];
    float z = pos[3 * i + 2];
    sx += x; sy += y; sz += z;
    sxx = fmaf(x, x, sxx); syy = fmaf(y, y, syy); szz = fmaf(z, z, szz);
    sxy = fmaf(x, y, sxy); sxz = fmaf(x, z, sxz); syz = fmaf(y, z, syz);
  }
  // 8-lane butterfly reductions (3 steps each)
#define RED8(v)                                                              \
  v += __shfl_xor(v, 1); v += __shfl_xor(v, 2); v += __shfl_xor(v, 4);
  RED8(sx) RED8(sy) RED8(sz)
  RED8(sxx) RED8(syy) RED8(szz)
  RED8(sxy) RED8(sxz) RED8(syz)
#undef RED8

  float fn = (float)(cnt > 0 ? cnt : 1);
  float inv = 1.0f / fn;
  float mx = sx * inv, my = sy * inv, mz = sz * inv;
  // central second moments: Sab = sum(ab) - n*ma*mb
  float Sxx = fmaf(-fn * mx, mx, sxx);
  float Syy = fmaf(-fn * my, my, syy);
  float Szz = fmaf(-fn * mz, mz, szz);
  float Sxy = fmaf(-fn * mx, my, sxy);
  float Sxz = fmaf(-fn * mx, mz, sxz);
  float Syz = fmaf(-fn * my, mz, syz);

  // component select (no runtime array indexing); inertia I = tr(S)*Id - S
  float v = mx;                            // sub=0
  v = (sub == 1) ? my : v;
  v = (sub == 2) ? mz : v;
  v = (sub == 3) ? (Syy + Szz) : v;        // ixx
  v = (sub == 4) ? (Sxx + Szz) : v;        // iyy
  v = (sub == 5) ? (Sxx + Syy) : v;        // izz
  v = (sub == 6) ? (-Sxy) : v;             // ixy
  v = (sub == 7) ? (-Sxz) : v;             // ixz
  wsf[sub * G + gid] = v;                  // comps 0..7
  if (sub == 0) wsf[8 * G + gid] = -Syz;   // comp 8 (iyz)
}

// ---------------------------------------------------------------------------
// Branch-free 3x3 symmetric Jacobi eigensolver in f32, 5 cyclic sweeps.
// Columns of Q = eigenvectors; eigenvalues sorted ascending (matches eigh).
// ---------------------------------------------------------------------------
__device__ __forceinline__ void jacobi3_f32(float a00, float a11, float a22,
                                            float a01, float a02, float a12,
                                            float Q[3][3]) {
  float A00 = a00, A11 = a11, A22 = a22;
  float A01 = a01, A02 = a02, A12 = a12;
  float Q00 = 1.f, Q01 = 0.f, Q02 = 0.f;
  float Q10 = 0.f, Q11 = 1.f, Q12 = 0.f;
  float Q20 = 0.f, Q21 = 0.f, Q22 = 1.f;

#define ROT(App, Aqq, Apq, Akp, Akq, Qrp0, Qrq0, Qrp1, Qrq1, Qrp2, Qrq2)     \
  {                                                                          \
    float apq = Apq;                                                         \
    float theta = (Aqq - App) / (2.0f * apq);                                \
    float t = copysignf(1.0f, theta) /                                       \
              (fabsf(theta) + sqrtf(1.0f + theta * theta));                  \
    t = (apq == 0.0f) ? 0.0f : t; /* kills 0/0 NaN path */                   \
    float c = 1.0f / sqrtf(1.0f + t * t);                                    \
    float s = t * c;                                                         \
    App = App - t * apq;                                                     \
    Aqq = Aqq + t * apq;                                                     \
    Apq = 0.0f;                                                              \
    float akp = Akp, akq = Akq;                                              \
    Akp = c * akp - s * akq;                                                 \
    Akq = s * akp + c * akq;                                                 \
    float r0p = Qrp0, r0q = Qrq0;                                            \
    Qrp0 = c * r0p - s * r0q;                                                \
    Qrq0 = s * r0p + c * r0q;                                                \
    float r1p = Qrp1, r1q = Qrq1;                                            \
    Qrp1 = c * r1p - s * r1q;                                                \
    Qrq1 = s * r1p + c * r1q;                                                \
    float r2p = Qrp2, r2q = Qrq2;                                            \
    Qrp2 = c * r2p - s * r2q;                                                \
    Qrq2 = s * r2p + c * r2q;                                                \
  }

#pragma unroll
  for (int sweep = 0; sweep < 5; ++sweep) {
    ROT(A00, A11, A01, A02, A12, Q00, Q01, Q10, Q11, Q20, Q21);
    ROT(A00, A22, A02, A01, A12, Q00, Q02, Q10, Q12, Q20, Q22);
    ROT(A11, A22, A12, A01, A02, Q01, Q02, Q11, Q12, Q21, Q22);
  }
#undef ROT

  float w0 = A00, w1 = A11, w2 = A22;
#define CSWAP(wa, wb, qa0, qb0, qa1, qb1, qa2, qb2)                          \
  {                                                                          \
    bool sw = (wb) < (wa);                                                   \
    float tw = wa; wa = sw ? wb : wa; wb = sw ? tw : wb;                     \
    float t0 = qa0; qa0 = sw ? qb0 : qa0; qb0 = sw ? t0 : qb0;               \
    float t1 = qa1; qa1 = sw ? qb1 : qa1; qb1 = sw ? t1 : qb1;               \
    float t2 = qa2; qa2 = sw ? qb2 : qa2; qb2 = sw ? t2 : qb2;               \
  }
  CSWAP(w0, w1, Q00, Q01, Q10, Q11, Q20, Q21);
  CSWAP(w1, w2, Q01, Q02, Q11, Q12, Q21, Q22);
  CSWAP(w0, w1, Q00, Q01, Q10, Q11, Q20, Q21);
#undef CSWAP

  Q[0][0] = Q00; Q[0][1] = Q01; Q[0][2] = Q02;
  Q[1][0] = Q10; Q[1][1] = Q11; Q[1][2] = Q12;
  Q[2][0] = Q20; Q[2][1] = Q21; Q[2][2] = Q22;
}

// ---------------------------------------------------------------------------
// Kernel B: one thread per graph. Jacobi + serial sign scan + epilogue.
// ---------------------------------------------------------------------------
__global__ __launch_bounds__(256) void eigen_kernel(
    const float* __restrict__ pos, const int* __restrict__ wsi,
    const float* __restrict__ wsf, float* __restrict__ out, int G) {
  int g = (int)(blockIdx.x * (unsigned)blockDim.x + threadIdx.x);
  if (g >= G) return;

  int s = wsi[g];
  int e = wsi[g + 1];

  float cx  = wsf[0 * G + g];
  float cy  = wsf[1 * G + g];
  float cz  = wsf[2 * G + g];
  float ixx = wsf[3 * G + g];
  float iyy = wsf[4 * G + g];
  float izz = wsf[5 * G + g];
  float ixy = wsf[6 * G + g];
  float ixz = wsf[7 * G + g];
  float iyz = wsf[8 * G + g];

  float Q[3][3];
  jacobi3_f32(ixx, iyy, izz, ixy, ixz, iyz, Q);

  float q00 = Q[0][0], q10 = Q[1][0], q20 = Q[2][0];
  float q01 = Q[0][1], q11 = Q[1][1], q21 = Q[2][1];

  // first atom (original order) with |proj| > EPS, axes 0 and 1 independent
  bool found0 = false, found1 = false;
  float v0 = 0.f, v1 = 0.f;
  for (int i = s; i < e; ++i) {
    float x = pos[3 * i + 0] - cx;
    float y = pos[3 * i + 1] - cy;
    float z = pos[3 * i + 2] - cz;
    float p0 = x * q00 + y * q10 + z * q20;
    float p1 = x * q01 + y * q11 + z * q21;
    if (!found0 && fabsf(p0) > CANON_EPS) { v0 = p0; found0 = true; }
    if (!found1 && fabsf(p1) > CANON_EPS) { v1 = p1; found1 = true; }
    if (found0 && found1) break;
  }
  float s0 = (found0 && v0 < 0.f) ? -1.f : 1.f;
  float s1 = (found1 && v1 < 0.f) ? -1.f : 1.f;

  float q0x = q00 * s0, q0y = q10 * s0, q0z = q20 * s0;
  float q1x = q01 * s1, q1y = q11 * s1, q1z = q21 * s1;
  float q2x = q0y * q1z - q0z * q1y;
  float q2y = q0z * q1x - q0x * q1z;
  float q2z = q0x * q1y - q0y * q1x;
  float* o = out + (size_t)g * 9;
  o[0] = q0x; o[1] = q1x; o[2] = q2x;
  o[3] = q0y; o[4] = q1y; o[5] = q2y;
  o[6] = q0z; o[7] = q1z; o[8] = q2z;
}

extern "C" void kernel_launch(void* const* d_in, const int* in_sizes, int n_in,
                              void* d_out, int out_size, void* d_ws, size_t ws_size,
                              hipStream_t stream) {
  const float* pos = (const float*)d_in[0];
  const int* batch = (const int*)d_in[1];
  float* out = (float*)d_out;

  int n = in_sizes[0] / 3;  // N atoms
  int G = out_size / 9;     // graphs

  int* wsi = (int*)d_ws;  // (G+1) ints: graph start offsets
  float* wsf = (float*)((char*)d_ws + (((size_t)(G + 1) * 4 + 255) & ~255ull));
  // wsf: 9 * G floats, SoA

  // Kernel A: 8 lanes/graph -> 32 graphs per 256-thread block
  int blocksA = (G * 8 + 255) / 256;
  moments_kernel<<<blocksA, 256, 0, stream>>>(pos, batch, wsi, wsf, n, G);

  // Kernel B: 1 thread/graph
  eigen_kernel<<<(G + 255) / 256, 256, 0, stream>>>(pos, wsi, wsf, out, G);
}